// Round 1
// baseline (20559.984 us; speedup 1.0000x reference)
//
#include <hip/hip_runtime.h>
#include <hip/hip_bf16.h>
#include <math.h>

#define Bz 64
#define Tz 256
#define Dz 512
#define Hz 1024
#define G3 (3*Hz)
#define G2 (2*Hz)

#define THREADS 256
#define KCHUNK 128
#define LDA 132   // padded LDS row stride in words; 132*4=528 B, 16B aligned, bank=(4b+k)%32

__device__ __forceinline__ float sigm(float x){ return 1.0f/(1.0f+expf(-x)); }

// ig load/store helpers (f32 or bf16 storage)
__device__ __forceinline__ float ld_ig(const float* p, size_t i){ return p[i]; }
__device__ __forceinline__ float ld_ig(const __hip_bfloat16* p, size_t i){ return __bfloat162float(p[i]); }
__device__ __forceinline__ void st_ig(float* p, size_t i, float v){ p[i]=v; }
__device__ __forceinline__ void st_ig(__hip_bfloat16* p, size_t i, float v){ p[i]=__float2bfloat16(v); }

// Skinny GEMM core: C[64 rows, COLS cols per wave] = A[64,KDIM] @ W[N,KDIM]^T tile.
// A staged in LDS (chunked over K); W read via wave-uniform (scalar) loads.
// lane b = row; jc0 = wave-uniform first column.
template<int COLS, int KDIM>
__device__ __forceinline__ void gemm_core(const float* __restrict__ Abase, int rowStride,
                                          const float* __restrict__ W,
                                          int jc0, int b, int tid,
                                          float* __restrict__ acc, float* __restrict__ lds)
{
#pragma unroll
  for (int c=0;c<COLS;c++) acc[c]=0.0f;
  constexpr int C4 = KCHUNK/4;
  for (int kb=0; kb<KDIM; kb+=KCHUNK) {
    __syncthreads();
    // stage A[0..63][kb..kb+KCHUNK) into LDS
    for (int i = tid; i < Bz*C4; i += THREADS) {
      int r  = i / C4;
      int c4 = i % C4;
      float4 v = *(const float4*)(Abase + (size_t)r*rowStride + kb + c4*4);
      *(float4*)(lds + r*LDA + c4*4) = v;
    }
    __syncthreads();
    const float* arow  = lds + b*LDA;
    const float* wbase = W + (size_t)jc0*KDIM + kb;
    for (int k=0;k<KCHUNK;k+=4) {
      float4 a = *(const float4*)(arow + k);
#pragma unroll
      for (int c=0;c<COLS;c++) {
        float4 w = *(const float4*)(wbase + (size_t)c*KDIM + k);
        acc[c] = fmaf(a.x,w.x,acc[c]);
        acc[c] = fmaf(a.y,w.y,acc[c]);
        acc[c] = fmaf(a.z,w.z,acc[c]);
        acc[c] = fmaf(a.w,w.w,acc[c]);
      }
    }
  }
}

// ---- input GEMM: ig[t][b][j] = x[b][t][:] . Wi[j][:] + bi[j]
template<typename IGT>
__global__ __launch_bounds__(THREADS)
void kA(const float* __restrict__ x, const float* __restrict__ Wi, const float* __restrict__ bi,
        IGT* __restrict__ ig)
{
  __shared__ float lds[Bz*LDA];
  int t = blockIdx.y;
  int tid = threadIdx.x;
  int b = tid & 63;
  int wv = __builtin_amdgcn_readfirstlane(tid >> 6);
  int jc0 = blockIdx.x*32 + wv*8;
  float acc[8];
  gemm_core<8, Dz>(x + (size_t)t*Dz, Tz*Dz, Wi, jc0, b, tid, acc, lds);
  size_t rowo = ((size_t)t*Bz + b)*G3;
#pragma unroll
  for (int c=0;c<8;c++){ int j=jc0+c; st_ig(ig, rowo + j, acc[c] + bi[j]); }
}

// ---- peephole GEMM: p[b][j] = ctx[b][:] . Wp[j][:] + bp[j]
__global__ __launch_bounds__(THREADS)
void kP(const float* __restrict__ ctx, const float* __restrict__ Wp, const float* __restrict__ bp,
        float* __restrict__ p)
{
  __shared__ float lds[Bz*LDA];
  int tid=threadIdx.x; int b=tid&63;
  int wv=__builtin_amdgcn_readfirstlane(tid>>6);
  int jc0 = blockIdx.x*16 + wv*4;
  float acc[4];
  gemm_core<4, Hz>(ctx, Hz, Wp, jc0, b, tid, acc, lds);
#pragma unroll
  for(int c=0;c<4;c++){ int j=jc0+c; p[(size_t)b*G3 + j] = acc[c] + bp[j]; }
}

// ---- step phase 1: gates1 = h@Wh.T ; r,i = sigmoid(. + ig + p); store r*h and i
template<typename IGT>
__global__ __launch_bounds__(THREADS)
void k1(const float* __restrict__ h, const float* __restrict__ Wh, const float* __restrict__ bh,
        const IGT* __restrict__ ig_t, const float* __restrict__ p,
        float* __restrict__ rh, float* __restrict__ inp)
{
  __shared__ float lds[Bz*LDA];
  int tid=threadIdx.x; int b=tid&63;
  int wv=__builtin_amdgcn_readfirstlane(tid>>6);
  int jc0 = blockIdx.x*16 + wv*4;
  float acc[4];
  gemm_core<4, Hz>(h, Hz, Wh, jc0, b, tid, acc, lds);
#pragma unroll
  for(int c=0;c<4;c++){
    int j=jc0+c;
    // for j<H this indexes the r-block of ig/p; for H<=j<2H the i-block — same flat index j.
    float g = acc[c] + bh[j] + ld_ig(ig_t,(size_t)b*G3 + j) + p[(size_t)b*G3 + j];
    float v = sigm(g);
    if (j < Hz) rh[(size_t)b*Hz + j] = v * h[(size_t)b*Hz + j];
    else        inp[(size_t)b*Hz + (j-Hz)] = v;
  }
}

// ---- step phase 2: h_n = (r*h)@Wc.T ; n = tanh(. + ig_n + p_n); hy = h + i*(n-h)
template<typename IGT>
__global__ __launch_bounds__(THREADS)
void k2(const float* __restrict__ rh, const float* __restrict__ Wc, const float* __restrict__ bc,
        const IGT* __restrict__ ig_t, const float* __restrict__ p,
        const float* __restrict__ h, const float* __restrict__ inp,
        float* __restrict__ hnext, float* __restrict__ out, int t)
{
  __shared__ float lds[Bz*LDA];
  int tid=threadIdx.x; int b=tid&63;
  int wv=__builtin_amdgcn_readfirstlane(tid>>6);
  int jc0 = blockIdx.x*16 + wv*4;
  float acc[4];
  gemm_core<4, Hz>(rh, Hz, Wc, jc0, b, tid, acc, lds);
#pragma unroll
  for(int c=0;c<4;c++){
    int j=jc0+c;
    float g = acc[c] + bc[j] + ld_ig(ig_t,(size_t)b*G3 + 2*Hz + j) + p[(size_t)b*G3 + 2*Hz + j];
    float n = tanhf(g);
    float hp = h[(size_t)b*Hz + j];
    float iv = inp[(size_t)b*Hz + j];
    float hy = hp + iv*(n - hp);
    hnext[(size_t)b*Hz + j] = hy;
    out[((size_t)b*Tz + t)*Hz + j] = hy;
  }
}

template<typename IGT>
static void run_all(const float* x, const float* h0, const float* ctx,
                    const float* Wi, const float* bi, const float* Wh, const float* bh,
                    const float* Wp, const float* bp, const float* Wc, const float* bc,
                    float* out, float* p, float* rh, float* inp, float* hb0, float* hb1,
                    void* igraw, hipStream_t stream)
{
  IGT* ig = (IGT*)igraw;
  kA<IGT><<<dim3(G3/32, Tz), THREADS, 0, stream>>>(x, Wi, bi, ig);
  kP<<<dim3(G3/16), THREADS, 0, stream>>>(ctx, Wp, bp, p);
  hipMemcpyAsync(hb0, h0, (size_t)Bz*Hz*sizeof(float), hipMemcpyDeviceToDevice, stream);
  const float* hc = hb0; float* hn = hb1;
  for (int t=0; t<Tz; t++) {
    const IGT* igt = ig + (size_t)t*Bz*G3;
    k1<IGT><<<dim3(G2/16), THREADS, 0, stream>>>(hc, Wh, bh, igt, p, rh, inp);
    k2<IGT><<<dim3(Hz/16), THREADS, 0, stream>>>(rh, Wc, bc, igt, p, hc, inp, hn, out, t);
    float* tmp = (float*)hc; hc = hn; hn = tmp;
  }
  hipMemcpyAsync(out + (size_t)Bz*Tz*Hz, hc, (size_t)Bz*Hz*sizeof(float),
                 hipMemcpyDeviceToDevice, stream);
}

extern "C" void kernel_launch(void* const* d_in, const int* in_sizes, int n_in,
                              void* d_out, int out_size, void* d_ws, size_t ws_size,
                              hipStream_t stream)
{
  const float* x   = (const float*)d_in[0];
  const float* h0  = (const float*)d_in[1];
  const float* ctx = (const float*)d_in[2];
  const float* Wi  = (const float*)d_in[3];
  const float* bi  = (const float*)d_in[4];
  const float* Wh  = (const float*)d_in[5];
  const float* bh  = (const float*)d_in[6];
  const float* Wp  = (const float*)d_in[7];
  const float* bp  = (const float*)d_in[8];
  const float* Wc  = (const float*)d_in[9];
  const float* bc  = (const float*)d_in[10];
  float* out = (float*)d_out;

  char* w = (char*)d_ws;
  float* p   = (float*)w; w += (size_t)Bz*G3*sizeof(float);
  float* rh  = (float*)w; w += (size_t)Bz*Hz*sizeof(float);
  float* inp = (float*)w; w += (size_t)Bz*Hz*sizeof(float);
  float* hb0 = (float*)w; w += (size_t)Bz*Hz*sizeof(float);
  float* hb1 = (float*)w; w += (size_t)Bz*Hz*sizeof(float);
  void* igraw = (void*)w;
  size_t auxBytes = (size_t)(w - (char*)d_ws);
  size_t igElems = (size_t)Tz*Bz*G3;
  bool f32ig = (ws_size >= auxBytes + igElems*sizeof(float));

  if (f32ig) {
    run_all<float>(x,h0,ctx,Wi,bi,Wh,bh,Wp,bp,Wc,bc, out, p,rh,inp,hb0,hb1, igraw, stream);
  } else {
    run_all<__hip_bfloat16>(x,h0,ctx,Wi,bi,Wh,bh,Wp,bp,Wc,bc, out, p,rh,inp,hb0,hb1, igraw, stream);
  }
}